// Round 1
// baseline (503.295 us; speedup 1.0000x reference)
//
#include <hip/hip_runtime.h>

// LSTM cell fused as one GEMM: Z[B,2048] = [input|h0] (bf16) @ Wint^T (bf16)
// Wint column order c: h_group = c>>6, gate = (c>>4)&3, h_low = c&15
//   => each wave's four 16-col MFMA subtiles are gates i,f,o,g at the SAME h,
//      so the gate nonlinearity fuses into the epilogue lane-locally.
// This version fuses the fp32->bf16 A-pack INTO the GEMM (no pack_X pass):
//   A staged reg-side (global fp32 -> cvt_pk -> ds_write_b128, XOR-swizzled),
//   B staged via global_load_lds with pre-swizzled SOURCE column (rule #21),
//   both operands read with koff = (quad ^ ((lrow>>1)&3))*8  -> <=2-way banks.
// B=32768, E=H=512, K=E+H=1024, N=4H=2048.

#define BQ 32768
#define HQ 512
#define KK 1024
#define BH (32768 * 512)  // 16777216 elements per output

typedef __bf16 bf16x8 __attribute__((ext_vector_type(8)));
typedef float f32x4 __attribute__((ext_vector_type(4)));

__device__ __forceinline__ unsigned short f2bf(float f) {
    unsigned int u = __float_as_uint(f);
    unsigned int r = (u + 0x7fffu + ((u >> 16) & 1u)) >> 16;
    return (unsigned short)r;
}

__device__ __forceinline__ void gld_lds16(const unsigned short* g, unsigned short* l) {
    __builtin_amdgcn_global_load_lds(
        (const __attribute__((address_space(1))) void*)g,
        (__attribute__((address_space(3))) void*)l,
        16, 0, 0);
}

__device__ __forceinline__ bf16x8 cvt8(f32x4 a, f32x4 b) {
    bf16x8 w;
    w[0] = (__bf16)a[0]; w[1] = (__bf16)a[1]; w[2] = (__bf16)a[2]; w[3] = (__bf16)a[3];
    w[4] = (__bf16)b[0]; w[5] = (__bf16)b[1]; w[6] = (__bf16)b[2]; w[7] = (__bf16)b[3];
    return w;
}

// ---- prepass: weight packing only (8 MiB read, trivial) --------------------

__global__ __launch_bounds__(256) void pack_W(const float* __restrict__ Wx,
                                              const float* __restrict__ Wh,
                                              const float* __restrict__ bx,
                                              const float* __restrict__ bh,
                                              unsigned short* __restrict__ Wint,
                                              float* __restrict__ biasc) {
    int j = blockIdx.x * 256 + threadIdx.x;  // 2048 rows * 256 quads
    int c = j >> 8;
    int kc = (j & 255) * 4;
    int gate = (c >> 4) & 3;
    int h = ((c >> 6) << 4) + (c & 15);
    const float* src = (kc < 512)
        ? (Wx + ((size_t)gate * 512 + h) * 512 + kc)
        : (Wh + ((size_t)gate * 512 + h) * 512 + (kc - 512));
    float4 v = *(const float4*)src;
    ushort4 o;
    o.x = f2bf(v.x); o.y = f2bf(v.y); o.z = f2bf(v.z); o.w = f2bf(v.w);
    *(ushort4*)&Wint[(size_t)c * 1024 + kc] = o;
    if ((j & 255) == 0) biasc[c] = bx[gate * 512 + h] + bh[gate * 512 + h];
}

// ---- fused GEMM + LSTM epilogue --------------------------------------------
// 128x128 tile, BK=32, 4 waves in 2x2; wave tile 64x64 = 4x4 MFMA 16x16x32.
// A: fp32 loaded from input/h0 directly, converted in-kernel (T14 prefetch).

__global__ __launch_bounds__(256, 4) void lstm_gemm(const float* __restrict__ xin,
                                                    const float* __restrict__ hin,
                                                    const unsigned short* __restrict__ Wint,
                                                    const float* __restrict__ biasc,
                                                    const float* __restrict__ c0,
                                                    float* __restrict__ out) {
    __shared__ __align__(16) unsigned short ldsA[128 * 32];
    __shared__ __align__(16) unsigned short ldsB[128 * 32];

    const int tid = threadIdx.x;
    const int lane = tid & 63;
    const int wave = tid >> 6;
    const int wm = wave >> 1;   // 0..1 (row of wave grid)
    const int wn = wave & 1;    // 0..1 (col of wave grid)
    const int quad = lane >> 4; // 0..3
    const int lrow = lane & 15; // 0..15

    const int bn = blockIdx.x;          // 0..15
    const int bm = blockIdx.y;          // 0..255
    const int m0 = bm * 128;
    const int n0 = bn * 128;

    // ---- A staging: thread t owns row tid>>1, 16-float half tid&1 of the
    //      32-col K-tile. fp32 load -> cvt -> ds_write_b128, XOR-swizzled.
    const int arow = tid >> 1;          // 0..127
    const int ahalf = tid & 1;
    const int aswz = (arow >> 1) & 3;
    const float* gAx = xin + (size_t)(m0 + arow) * HQ + ahalf * 16;
    const float* gAh = hin + (size_t)(m0 + arow) * HQ + ahalf * 16;
    unsigned short* wA0 = &ldsA[arow * 32 + (((ahalf * 2 + 0) ^ aswz) * 8)];
    unsigned short* wA1 = &ldsA[arow * 32 + (((ahalf * 2 + 1) ^ aswz) * 8)];

    // ---- B staging: global_load_lds, linear LDS dest (tid*16B), source
    //      column 16B-unit pre-swizzled so LDS holds unit g at slot g^((row>>1)&3).
    const int brow = tid >> 2;          // 0..63
    const int bunit = (tid & 3) ^ ((tid >> 3) & 3);
    const unsigned short* gB = Wint + (size_t)(n0 + brow) * KK + bunit * 8;

    // ---- fragment read offset: LDS unit quad^((row>>1)&3) holds global unit quad
    const int koff = (quad ^ ((lrow >> 1) & 3)) * 8;

    f32x4 acc[4][4];
    for (int i = 0; i < 4; i++)
        for (int j = 0; j < 4; j++) {
            f32x4 z = {0.f, 0.f, 0.f, 0.f};
            acc[i][j] = z;
        }

    // prologue: prefetch A regs for kt=0 (kt<512 -> from input)
    f32x4 r0 = *(const f32x4*)(gAx + 0);
    f32x4 r1 = *(const f32x4*)(gAx + 4);
    f32x4 r2 = *(const f32x4*)(gAx + 8);
    f32x4 r3 = *(const f32x4*)(gAx + 12);

    for (int kt = 0; kt < KK; kt += 32) {
        // issue B stage for this K-tile, write converted A from regs
        gld_lds16(gB + kt, &ldsB[tid * 8]);
        gld_lds16(gB + (size_t)64 * KK + kt, &ldsB[2048 + tid * 8]);
        *(bf16x8*)wA0 = cvt8(r0, r1);
        *(bf16x8*)wA1 = cvt8(r2, r3);
        __syncthreads();

        // T14: issue next K-tile's A loads now; they complete under the MFMAs
        const int kn = kt + 32;
        if (kn < KK) {
            const float* p = (kn < 512) ? (gAx + kn) : (gAh + (kn - 512));
            r0 = *(const f32x4*)(p + 0);
            r1 = *(const f32x4*)(p + 4);
            r2 = *(const f32x4*)(p + 8);
            r3 = *(const f32x4*)(p + 12);
        }

        bf16x8 af[4], bfr[4];
        for (int mi = 0; mi < 4; mi++)
            af[mi] = *(const bf16x8*)&ldsA[(wm * 64 + mi * 16 + lrow) * 32 + koff];
        for (int ni = 0; ni < 4; ni++)
            bfr[ni] = *(const bf16x8*)&ldsB[(wn * 64 + ni * 16 + lrow) * 32 + koff];
        for (int mi = 0; mi < 4; mi++)
            for (int ni = 0; ni < 4; ni++)
                acc[mi][ni] = __builtin_amdgcn_mfma_f32_16x16x32_bf16(
                    af[mi], bfr[ni], acc[mi][ni], 0, 0, 0);
        __syncthreads();
    }

    // epilogue: lane owns gates i,f,o,g (ni=0..3) at h fixed per lane
    float bi[4];
    for (int ni = 0; ni < 4; ni++)
        bi[ni] = biasc[n0 + wn * 64 + ni * 16 + lrow];
    const int h = (bn * 2 + wn) * 16 + lrow;

    for (int mi = 0; mi < 4; mi++) {
        for (int r = 0; r < 4; r++) {
            int b = m0 + wm * 64 + mi * 16 + quad * 4 + r;
            float zi = acc[mi][0][r] + bi[0];
            float zf = acc[mi][1][r] + bi[1];
            float zo = acc[mi][2][r] + bi[2];
            float zg = acc[mi][3][r] + bi[3];
            float ig = 1.f / (1.f + __expf(-zi));
            float fg = 1.f / (1.f + __expf(-zf));
            float og = 1.f / (1.f + __expf(-zo));
            float gg = 1.f - 2.f / (__expf(2.f * zg) + 1.f);  // tanh, stable both ends
            float c0v = c0[(size_t)b * HQ + h];
            float c1 = fg * c0v + ig * gg;
            float th = 1.f - 2.f / (__expf(2.f * c1) + 1.f);
            out[(size_t)b * HQ + h] = og * th;                 // h1
            out[(size_t)BH + (size_t)b * HQ + h] = c1;         // c1
        }
    }
}

extern "C" void kernel_launch(void* const* d_in, const int* in_sizes, int n_in,
                              void* d_out, int out_size, void* d_ws, size_t ws_size,
                              hipStream_t stream) {
    (void)in_sizes; (void)n_in; (void)out_size; (void)ws_size;
    const float* input = (const float*)d_in[0];
    const float* h0    = (const float*)d_in[1];
    const float* c0    = (const float*)d_in[2];
    const float* Wx    = (const float*)d_in[3];
    const float* bx    = (const float*)d_in[4];
    const float* Wh    = (const float*)d_in[5];
    const float* bh    = (const float*)d_in[6];
    float* out = (float*)d_out;

    char* ws = (char*)d_ws;
    unsigned short* Wint = (unsigned short*)ws;                      // 4 MiB
    float* biasc = (float*)(ws + (size_t)4 * 1024 * 1024);           // 8 KiB

    pack_W<<<2048, 256, 0, stream>>>(Wx, Wh, bx, bh, Wint, biasc);
    lstm_gemm<<<dim3(16, 256), 256, 0, stream>>>(input, h0, Wint, biasc, c0, out);
}